// Round 1
// baseline (244.287 us; speedup 1.0000x reference)
//
#include <hip/hip_runtime.h>
#include <math.h>

#define NPIX 4096

__device__ __forceinline__ float gelu_exact(float x) {
    return 0.5f * x * (1.0f + erff(x * 0.70710678118654752440f));
}

// 3x3 conv (cross-correlation), stride 1, zero-pad 1, 3 in / 3 out channels.
// src: [3][64][64], w: [o][i][3][3] flat.
__device__ __forceinline__ float conv3_tap(const float* __restrict__ src,
                                           const float* __restrict__ w,
                                           int o, int y, int x) {
    float acc = 0.f;
#pragma unroll
    for (int ci = 0; ci < 3; ++ci) {
#pragma unroll
        for (int dy = 0; dy < 3; ++dy) {
            int yy = y + dy - 1;
            if (yy < 0 || yy >= 64) continue;
#pragma unroll
            for (int dx = 0; dx < 3; ++dx) {
                int xx = x + dx - 1;
                if (xx < 0 || xx >= 64) continue;
                acc = fmaf(src[ci*NPIX + yy*64 + xx], w[o*27 + ci*9 + dy*3 + dx], acc);
            }
        }
    }
    return acc;
}

// ---------------------------------------------------------------- kA
// blocks 0..47: t1 = gelu(conv(x, pe_w1))   [3][64][64]
// block 48: precompute per-head 3x3 matrices
//   M_h = Wq_h Wk_h^T * log2(e)/sqrt(32)   (72 floats)
//   T_h = Wv_h Pr_h                         (72 floats)
__global__ void kA(const float* __restrict__ x, const float* __restrict__ pew1,
                   const float* __restrict__ qsw, const float* __restrict__ psw,
                   float* __restrict__ t1, float* __restrict__ MT) {
    int b = blockIdx.x, tid = threadIdx.x;
    if (b < 48) {
        int idx = b*256 + tid;
        int c = idx >> 12, rem = idx & 4095;
        t1[idx] = gelu_exact(conv3_tap(x, pew1, c, rem >> 6, rem & 63));
    } else if (tid < 144) {
        int isT = tid >= 72;
        int u = isT ? tid - 72 : tid;
        int h = u / 9, i = (u % 9) / 3, j = u % 3;
        float acc = 0.f;
        if (!isT) {
            const float* wq = qsw + i*768 + h*32;        // q cols 0..255
            const float* wk = qsw + j*768 + 256 + h*32;  // k cols 256..511
#pragma unroll
            for (int d = 0; d < 32; ++d) acc = fmaf(wq[d], wk[d], acc);
            acc *= 1.4426950408889634f * 0.17677669529663687f; // log2(e)/sqrt(32)
        } else {
            const float* wv = qsw + i*768 + 512 + h*32;  // v cols 512..767
#pragma unroll
            for (int d = 0; d < 32; ++d) acc = fmaf(wv[d], psw[(h*32 + d)*3 + j], acc);
        }
        MT[tid] = acc;
    }
}

// ---------------------------------------------------------------- kB
// pos = conv(t1, pe_w2); per-pixel LN over the 3 channels -> sn [3][4096].
// Also zero the four atomic-accumulator buffers (ws is poisoned each launch).
__global__ void kB(const float* __restrict__ t1, const float* __restrict__ pew2,
                   const float* __restrict__ lg, const float* __restrict__ lb,
                   float* __restrict__ pos, float* __restrict__ sn,
                   float* __restrict__ z1, float* __restrict__ z2,
                   float* __restrict__ z3, float* __restrict__ z4) {
    int n = blockIdx.x*256 + threadIdx.x;   // 16 blocks * 256 = 4096 pixels
    int y = n >> 6, x = n & 63;
    float p0 = conv3_tap(t1, pew2, 0, y, x);
    float p1 = conv3_tap(t1, pew2, 1, y, x);
    float p2 = conv3_tap(t1, pew2, 2, y, x);
    float mu = (p0 + p1 + p2) * (1.f/3.f);
    float d0 = p0 - mu, d1 = p1 - mu, d2 = p2 - mu;
    float r = rsqrtf((d0*d0 + d1*d1 + d2*d2) * (1.f/3.f) + 1e-5f);
    pos[n] = p0; pos[NPIX+n] = p1; pos[2*NPIX+n] = p2;
    sn[n]        = d0*r*lg[0] + lb[0];
    sn[NPIX+n]   = d1*r*lg[1] + lb[1];
    sn[2*NPIX+n] = d2*r*lg[2] + lb[2];
#pragma unroll
    for (int i = 0; i < 3; ++i) {
        z1[i*NPIX+n] = 0.f; z2[i*NPIX+n] = 0.f;
        z3[i*NPIX+n] = 0.f; z4[i*NPIX+n] = 0.f;
    }
}

// ---------------------------------------------------------------- kC1
// patch embed partial sums: pb[t][o] += sum_k patchvec_t[k0+k] * ew[o][k0+k]
// grid 24 = 3 o-chunks x 8 k-splits(96). All 16 tokens per block.
__global__ void kC1(const float* __restrict__ pos, const float* __restrict__ ew,
                    float* __restrict__ pb) {
    __shared__ float pv[16*96];
    int och = blockIdx.x % 3, ks = blockIdx.x / 3;
    int k0 = ks * 96, tid = threadIdx.x;
    for (int idx = tid; idx < 1536; idx += 256) {
        int t = idx / 96, k = idx % 96;
        int kk = k0 + k;
        int c = kk >> 8, p = (kk >> 4) & 15, q = kk & 15;
        int hp = t >> 2, wp = t & 3;
        pv[idx] = pos[c*NPIX + (hp*16 + p)*64 + wp*16 + q];
    }
    __syncthreads();
    int o = och*256 + tid;
    float acc[16];
#pragma unroll
    for (int t = 0; t < 16; ++t) acc[t] = 0.f;
    const float4* wr = (const float4*)(ew + o*768 + k0);
#pragma unroll 2
    for (int k4 = 0; k4 < 24; ++k4) {
        float4 w4 = wr[k4];
#pragma unroll
        for (int t = 0; t < 16; ++t) {
            const float* p4 = &pv[t*96 + k4*4];
            acc[t] = fmaf(w4.x, p4[0], acc[t]);
            acc[t] = fmaf(w4.y, p4[1], acc[t]);
            acc[t] = fmaf(w4.z, p4[2], acc[t]);
            acc[t] = fmaf(w4.w, p4[3], acc[t]);
        }
    }
#pragma unroll
    for (int t = 0; t < 16; ++t) atomicAdd(&pb[t*768 + o], acc[t]);
}

// ---------------------------------------------------------------- kC2
// pn = LayerNorm(pb + embed_b) * g + b, per token (16 blocks x 768 threads)
__global__ void kC2(const float* __restrict__ pb, const float* __restrict__ eb,
                    const float* __restrict__ g, const float* __restrict__ bb,
                    float* __restrict__ pn) {
    __shared__ float rs[12], rs2[12], stats[2];
    int t = blockIdx.x, tid = threadIdx.x;
    float v = pb[t*768 + tid] + eb[tid];
    float s = v, s2 = v*v;
#pragma unroll
    for (int o = 32; o >= 1; o >>= 1) { s += __shfl_xor(s, o); s2 += __shfl_xor(s2, o); }
    int wid = tid >> 6;
    if ((tid & 63) == 0) { rs[wid] = s; rs2[wid] = s2; }
    __syncthreads();
    if (tid == 0) {
        float S = 0.f, S2 = 0.f;
        for (int i = 0; i < 12; ++i) { S += rs[i]; S2 += rs2[i]; }
        float mu = S * (1.f/768.f);
        stats[0] = mu;
        stats[1] = rsqrtf(fmaxf(S2 * (1.f/768.f) - mu*mu, 0.f) + 1e-5f);
    }
    __syncthreads();
    pn[t*768 + tid] = (v - stats[0]) * stats[1] * g[tid] + bb[tid];
}

// ---------------------------------------------------------------- kD
// qkv partial: qkvp[t][o] += sum_k pn[t][k0+k] * qpw[k0+k][o]
// grid 48 = 3 o-chunks x 16 k-splits(48)
__global__ void kD(const float* __restrict__ pn, const float* __restrict__ qw,
                   float* __restrict__ qkvp) {
    __shared__ float ps[16*48];
    int och = blockIdx.x % 3, ks = blockIdx.x / 3;
    int k0 = ks * 48, tid = threadIdx.x;
    for (int idx = tid; idx < 768; idx += 256) {
        int t = idx / 48, k = idx % 48;
        ps[idx] = pn[t*768 + k0 + k];
    }
    __syncthreads();
    int o = och*256 + tid;
    float acc[16];
#pragma unroll
    for (int t = 0; t < 16; ++t) acc[t] = 0.f;
    for (int k = 0; k < 48; ++k) {
        float w = qw[(k0 + k)*768 + o];
#pragma unroll
        for (int t = 0; t < 16; ++t) acc[t] = fmaf(ps[t*48 + k], w, acc[t]);
    }
#pragma unroll
    for (int t = 0; t < 16; ++t) atomicAdd(&qkvp[t*768 + o], acc[t]);
}

// ---------------------------------------------------------------- kE
// patch attention: 1 block, 512 threads = 8 waves, wave h handles head h.
// qkv staged in LDS with padded stride 772 (772%32==4 -> 2-way max, free).
__global__ __launch_bounds__(512) void kE(const float* __restrict__ qkvp,
                                          float* __restrict__ attn) {
    __shared__ float qs[16*772];
    __shared__ float wsm[8][16][16];
    int tid = threadIdx.x;
    for (int i = tid; i < 3072; i += 512) {
        int n = i / 192, c4 = i % 192;
        ((float4*)&qs[n*772])[c4] = ((const float4*)qkvp)[i];
    }
    __syncthreads();
    int h = tid >> 6, l = tid & 63;
    int nn = l >> 2, mg = l & 3;
    const float* q = &qs[nn*772 + h*32];
    float sc[4];
#pragma unroll
    for (int mm = 0; mm < 4; ++mm) {
        int m = mg*4 + mm;
        const float* k = &qs[m*772 + 256 + h*32];
        float d = 0.f;
#pragma unroll
        for (int dd = 0; dd < 32; ++dd) d = fmaf(q[dd], k[dd], d);
        sc[mm] = d * 0.17677669529663687f;   // 1/sqrt(32)
    }
    float mx = fmaxf(fmaxf(sc[0], sc[1]), fmaxf(sc[2], sc[3]));
    mx = fmaxf(mx, __shfl_xor(mx, 1));
    mx = fmaxf(mx, __shfl_xor(mx, 2));
    float e[4]; float sum = 0.f;
#pragma unroll
    for (int mm = 0; mm < 4; ++mm) { e[mm] = expf(sc[mm] - mx); sum += e[mm]; }
    sum += __shfl_xor(sum, 1);
    sum += __shfl_xor(sum, 2);
    float inv = 1.f / sum;
#pragma unroll
    for (int mm = 0; mm < 4; ++mm) wsm[h][nn][mg*4 + mm] = e[mm] * inv;
    __syncthreads();
    // phase 2: out[h2][n2][d0..d0+7] ; each thread 8 outputs
    int flat = tid * 8;
    int h2 = flat >> 9, n2 = (flat >> 5) & 15, d0 = flat & 31;
    float out[8];
#pragma unroll
    for (int r = 0; r < 8; ++r) out[r] = 0.f;
#pragma unroll
    for (int m = 0; m < 16; ++m) {
        float ww = wsm[h2][n2][m];
        const float* v = &qs[m*772 + 512 + h2*32 + d0];
#pragma unroll
        for (int r = 0; r < 8; ++r) out[r] = fmaf(ww, v[r], out[r]);
    }
#pragma unroll
    for (int r = 0; r < 8; ++r) attn[n2*256 + h2*32 + d0 + r] = out[r];
}

// ---------------------------------------------------------------- kF1
// proj partial: op[t][o] += sum_k attn[t][k0+k] * ppw[k0+k][o]
// grid 12 = 3 o-chunks x 4 k-splits(64)
__global__ void kF1(const float* __restrict__ at, const float* __restrict__ pw,
                    float* __restrict__ op) {
    __shared__ float as_[16*64];
    int och = blockIdx.x % 3, ks = blockIdx.x / 3;
    int k0 = ks * 64, tid = threadIdx.x;
    for (int idx = tid; idx < 1024; idx += 256) {
        int t = idx >> 6, k = idx & 63;
        as_[idx] = at[t*256 + k0 + k];
    }
    __syncthreads();
    int o = och*256 + tid;
    float acc[16];
#pragma unroll
    for (int t = 0; t < 16; ++t) acc[t] = 0.f;
    for (int k = 0; k < 64; ++k) {
        float w = pw[(k0 + k)*768 + o];
#pragma unroll
        for (int t = 0; t < 16; ++t) acc[t] = fmaf(as_[t*64 + k], w, acc[t]);
    }
#pragma unroll
    for (int t = 0; t < 16; ++t) atomicAdd(&op[t*768 + o], acc[t]);
}

// ---------------------------------------------------------------- kF2
// recon (conv-transpose as einsum): outp[d][hp*16+i][wp*16+j] +=
//   sum_c (op[t][c]+ppb[c]) * rw[c][d*256+i*16+j]
// grid 24 = 3 dij-chunks x 8 c-splits(96)
__global__ void kF2(const float* __restrict__ op, const float* __restrict__ ppb,
                    const float* __restrict__ rw, float* __restrict__ outp) {
    __shared__ float os_[16*96];
    int dch = blockIdx.x % 3, cs = blockIdx.x / 3;
    int c0 = cs * 96, tid = threadIdx.x;
    for (int idx = tid; idx < 1536; idx += 256) {
        int t = idx / 96, k = idx % 96;
        os_[idx] = op[t*768 + c0 + k] + ppb[c0 + k];
    }
    __syncthreads();
    int dij = dch*256 + tid;
    float acc[16];
#pragma unroll
    for (int t = 0; t < 16; ++t) acc[t] = 0.f;
    for (int k = 0; k < 96; ++k) {
        float w = rw[(c0 + k)*768 + dij];
#pragma unroll
        for (int t = 0; t < 16; ++t) acc[t] = fmaf(os_[t*96 + k], w, acc[t]);
    }
    int d = dij >> 8, i = (dij >> 4) & 15, j = dij & 15;
#pragma unroll
    for (int t = 0; t < 16; ++t) {
        int hp = t >> 2, wp = t & 3;
        atomicAdd(&outp[d*NPIX + (hp*16 + i)*64 + wp*16 + j], acc[t]);
    }
}

// ---------------------------------------------------------------- kG
// pixel-branch attention via rank-3 factorization.
// grid 512 x 256: block = 8 pixels x 8 heads x 4 m-chunks.
// sn [3][4096] staged in LDS; inner loop: e = 2^(a . sn_m), accumulate
// Z, S (3-vec); out_seq[n] = sum_h (S/Z) T_h + psb.
__global__ __launch_bounds__(256) void kG(const float* __restrict__ snG,
                                          const float* __restrict__ MT,
                                          const float* __restrict__ psb,
                                          float* __restrict__ outs) {
    __shared__ float s[12288];
    __shared__ float Msh[72], Tsh[72];
    __shared__ float acc[8][3];
    int tid = threadIdx.x;
    for (int i = tid; i < 3072; i += 256)
        ((float4*)s)[i] = ((const float4*)snG)[i];
    if (tid < 72) Msh[tid] = MT[tid];
    else if (tid < 144) Tsh[tid - 72] = MT[tid];
    if (tid < 24) acc[tid / 3][tid % 3] = 0.f;
    __syncthreads();

    int pair = tid >> 2, chunk = tid & 3;
    int h = pair & 7, nl = pair >> 3;
    int n = blockIdx.x*8 + nl;
    float x0 = s[n], x1 = s[4096 + n], x2 = s[8192 + n];
    const float* M = &Msh[h*9];
    float a0 = x0*M[0] + x1*M[3] + x2*M[6];
    float a1 = x0*M[1] + x1*M[4] + x2*M[7];
    float a2 = x0*M[2] + x1*M[5] + x2*M[8];
    float Z = 0.f, S0 = 0.f, S1 = 0.f, S2 = 0.f;
#pragma unroll 4
    for (int t4 = 0; t4 < 1024; ++t4) {
        int m = t4*4 + chunk;                  // interleaved -> bank-conflict-free
        float v0 = s[m], v1 = s[4096 + m], v2 = s[8192 + m];
        float e = exp2f(fmaf(a0, v0, fmaf(a1, v1, a2 * v2)));
        Z += e;
        S0 = fmaf(e, v0, S0); S1 = fmaf(e, v1, S1); S2 = fmaf(e, v2, S2);
    }
#pragma unroll
    for (int o = 1; o <= 2; o <<= 1) {
        Z  += __shfl_xor(Z, o);  S0 += __shfl_xor(S0, o);
        S1 += __shfl_xor(S1, o); S2 += __shfl_xor(S2, o);
    }
    if (chunk == 0) {
        float inv = 1.f / Z;
        float r0 = S0*inv, r1 = S1*inv, r2 = S2*inv;
        const float* T = &Tsh[h*9];
        atomicAdd(&acc[nl][0], r0*T[0] + r1*T[3] + r2*T[6]);
        atomicAdd(&acc[nl][1], r0*T[1] + r1*T[4] + r2*T[7]);
        atomicAdd(&acc[nl][2], r0*T[2] + r1*T[5] + r2*T[8]);
    }
    __syncthreads();
    if (tid < 24) {
        int j = tid % 3, nn = tid / 3;
        outs[j*NPIX + blockIdx.x*8 + nn] = acc[nn][j] + psb[j];
    }
}

// ---------------------------------------------------------------- kH
// combined = outp + recon_b + outs ; t2 = gelu(conv(combined, pd_w1))
__global__ void kH(const float* __restrict__ outp, const float* __restrict__ outs,
                   const float* __restrict__ rb, const float* __restrict__ w,
                   float* __restrict__ t2) {
    int idx = blockIdx.x*256 + threadIdx.x;
    int c = idx >> 12, rem = idx & 4095;
    int y = rem >> 6, x = rem & 63;
    float acc = 0.f;
#pragma unroll
    for (int ci = 0; ci < 3; ++ci) {
        float bias = rb[ci];
#pragma unroll
        for (int dy = 0; dy < 3; ++dy) {
            int yy = y + dy - 1;
            if (yy < 0 || yy >= 64) continue;
#pragma unroll
            for (int dx = 0; dx < 3; ++dx) {
                int xx = x + dx - 1;
                if (xx < 0 || xx >= 64) continue;
                float cb = outp[ci*NPIX + yy*64 + xx] + bias + outs[ci*NPIX + yy*64 + xx];
                acc = fmaf(cb, w[c*27 + ci*9 + dy*3 + dx], acc);
            }
        }
    }
    t2[idx] = gelu_exact(acc);
}

// ---------------------------------------------------------------- kI
__global__ void kI(const float* __restrict__ t2, const float* __restrict__ w,
                   float* __restrict__ out) {
    int idx = blockIdx.x*256 + threadIdx.x;
    int c = idx >> 12, rem = idx & 4095;
    out[idx] = conv3_tap(t2, w, c, rem >> 6, rem & 63);
}

extern "C" void kernel_launch(void* const* d_in, const int* in_sizes, int n_in,
                              void* d_out, int out_size, void* d_ws, size_t ws_size,
                              hipStream_t stream) {
    (void)in_sizes; (void)n_in; (void)out_size; (void)ws_size;
    const float* x    = (const float*)d_in[0];
    const float* pew1 = (const float*)d_in[1];
    const float* pew2 = (const float*)d_in[2];
    const float* ew   = (const float*)d_in[3];
    const float* eb   = (const float*)d_in[4];
    const float* g1   = (const float*)d_in[5];
    const float* b1   = (const float*)d_in[6];
    const float* qpw  = (const float*)d_in[7];
    const float* ppw  = (const float*)d_in[8];
    const float* ppb  = (const float*)d_in[9];
    const float* rw   = (const float*)d_in[10];
    const float* rb   = (const float*)d_in[11];
    const float* g2   = (const float*)d_in[12];
    const float* b2   = (const float*)d_in[13];
    const float* qsw  = (const float*)d_in[14];
    const float* psw  = (const float*)d_in[15];
    const float* psb  = (const float*)d_in[16];
    const float* pdw1 = (const float*)d_in[17];
    const float* pdw2 = (const float*)d_in[18];

    float* ws   = (float*)d_ws;
    float* t1   = ws;            // 12288
    float* pos  = ws + 12288;    // 12288
    float* sn   = ws + 24576;    // 12288
    float* MT   = ws + 36864;    // 144
    float* pb   = ws + 37008;    // 12288 (atomic)
    float* pn   = ws + 49296;    // 12288
    float* qkvp = ws + 61584;    // 12288 (atomic)
    float* attn = ws + 73872;    // 4096
    float* op   = ws + 77968;    // 12288 (atomic)
    float* outp = ws + 90256;    // 12288 (atomic)
    float* outs = ws + 102544;   // 12288
    float* t2   = ws + 114832;   // 12288
    float* out  = (float*)d_out;

    kA<<<dim3(49),  dim3(256), 0, stream>>>(x, pew1, qsw, psw, t1, MT);
    kB<<<dim3(16),  dim3(256), 0, stream>>>(t1, pew2, g2, b2, pos, sn, pb, qkvp, op, outp);
    kC1<<<dim3(24), dim3(256), 0, stream>>>(pos, ew, pb);
    kC2<<<dim3(16), dim3(768), 0, stream>>>(pb, eb, g1, b1, pn);
    kD<<<dim3(48),  dim3(256), 0, stream>>>(pn, qpw, qkvp);
    kE<<<dim3(1),   dim3(512), 0, stream>>>(qkvp, attn);
    kF1<<<dim3(12), dim3(256), 0, stream>>>(attn, ppw, op);
    kF2<<<dim3(24), dim3(256), 0, stream>>>(op, ppb, rw, outp);
    kG<<<dim3(512), dim3(256), 0, stream>>>(sn, MT, psb, outs);
    kH<<<dim3(48),  dim3(256), 0, stream>>>(outp, outs, rb, pdw1, t2);
    kI<<<dim3(48),  dim3(256), 0, stream>>>(t2, pdw2, out);
}

// Round 2
// 203.716 us; speedup vs baseline: 1.1992x; 1.1992x over previous
//
#include <hip/hip_runtime.h>
#include <math.h>

#define NPIX 4096

#if __has_builtin(__builtin_amdgcn_exp2f)
#define EXP2(x) __builtin_amdgcn_exp2f(x)
#else
#define EXP2(x) exp2f(x)
#endif

__device__ __forceinline__ float gelu_exact(float x) {
    return 0.5f * x * (1.0f + erff(x * 0.70710678118654752440f));
}

// 3x3 conv tap from a global [3][64][64] image
__device__ __forceinline__ float conv3_tap(const float* __restrict__ src,
                                           const float* __restrict__ w,
                                           int o, int y, int x) {
    float acc = 0.f;
#pragma unroll
    for (int ci = 0; ci < 3; ++ci) {
#pragma unroll
        for (int dy = 0; dy < 3; ++dy) {
            int yy = y + dy - 1;
            if (yy < 0 || yy >= 64) continue;
#pragma unroll
            for (int dx = 0; dx < 3; ++dx) {
                int xx = x + dx - 1;
                if (xx < 0 || xx >= 64) continue;
                acc = fmaf(src[ci*NPIX + yy*64 + xx], w[o*27 + ci*9 + dy*3 + dx], acc);
            }
        }
    }
    return acc;
}

// ================================================================ kAB
// blocks 0..15: fused  t1 = gelu(conv(x,pe_w1)) [halo in LDS]  ->
//               pos = conv(t1,pe_w2) -> per-pixel LN -> sn.
//               Also zero the 4 atomic accumulator buffers.
// block 16: MT precompute (M_h scaled by log2e/sqrt(32), T_h = Wv_h Pr_h)
__global__ __launch_bounds__(256) void kAB(
        const float* __restrict__ x, const float* __restrict__ pew1,
        const float* __restrict__ pew2,
        const float* __restrict__ lg, const float* __restrict__ lb,
        const float* __restrict__ qsw, const float* __restrict__ psw,
        float* __restrict__ pos, float* __restrict__ sn, float* __restrict__ MT,
        float* __restrict__ z1, float* __restrict__ z2,
        float* __restrict__ z3, float* __restrict__ z4) {
    int b = blockIdx.x, tid = threadIdx.x;
    if (b == 16) {
        if (tid < 144) {
            int isT = tid >= 72;
            int u = isT ? tid - 72 : tid;
            int h = u / 9, i = (u % 9) / 3, j = u % 3;
            float acc = 0.f;
            if (!isT) {
                const float* wq = qsw + i*768 + h*32;
                const float* wk = qsw + j*768 + 256 + h*32;
#pragma unroll
                for (int d = 0; d < 32; ++d) acc = fmaf(wq[d], wk[d], acc);
                acc *= 1.4426950408889634f * 0.17677669529663687f;
            } else {
                const float* wv = qsw + i*768 + 512 + h*32;
#pragma unroll
                for (int d = 0; d < 32; ++d) acc = fmaf(wv[d], psw[(h*32 + d)*3 + j], acc);
            }
            MT[tid] = acc;
        }
        return;
    }
    __shared__ float t1l[3][8][64];
    int y0 = b * 4;
    // halo t1: rows y0-2 .. y0+5
    for (int i = tid; i < 1536; i += 256) {
        int c = i >> 9, rr = (i >> 6) & 7, xx = i & 63;
        int yg = y0 - 2 + rr;
        float v = 0.f;
        if (yg >= 0 && yg < 64) v = gelu_exact(conv3_tap(x, pew1, c, yg, xx));
        t1l[c][rr][xx] = v;
    }
    __syncthreads();
    int n = b*256 + tid;          // pixel id
    int yl = tid >> 6;            // 0..3  (global y = y0+yl)
    int xx = tid & 63;
    int yg = y0 + yl;
    float p[3];
#pragma unroll
    for (int o = 0; o < 3; ++o) {
        float acc = 0.f;
#pragma unroll
        for (int ci = 0; ci < 3; ++ci) {
#pragma unroll
            for (int dy = 0; dy < 3; ++dy) {
                int yy = yg + dy - 1;
                if (yy < 0 || yy >= 64) continue;
                int rl = yl + dy + 1;   // yy - (y0-2)
#pragma unroll
                for (int dx = 0; dx < 3; ++dx) {
                    int xc = xx + dx - 1;
                    if (xc < 0 || xc >= 64) continue;
                    acc = fmaf(t1l[ci][rl][xc], pew2[o*27 + ci*9 + dy*3 + dx], acc);
                }
            }
        }
        p[o] = acc;
    }
    float mu = (p[0] + p[1] + p[2]) * (1.f/3.f);
    float d0 = p[0]-mu, d1 = p[1]-mu, d2 = p[2]-mu;
    float r = rsqrtf((d0*d0 + d1*d1 + d2*d2) * (1.f/3.f) + 1e-5f);
    pos[n] = p[0]; pos[NPIX+n] = p[1]; pos[2*NPIX+n] = p[2];
    sn[n]        = d0*r*lg[0] + lb[0];
    sn[NPIX+n]   = d1*r*lg[1] + lb[1];
    sn[2*NPIX+n] = d2*r*lg[2] + lb[2];
#pragma unroll
    for (int j = 0; j < 3; ++j) {
        int idx = n*3 + j;
        z1[idx] = 0.f; z2[idx] = 0.f; z3[idx] = 0.f; z4[idx] = 0.f;
    }
}

// ================================================================ K2
// blocks 0..511 : kG  (pixel attention, head-shared rank-3 factorization)
// blocks 512..559: kC1 (patch embed partial sums, 3 o-chunks x 16 k-splits)
__global__ __launch_bounds__(256) void K2(
        const float* __restrict__ snG, const float* __restrict__ MT,
        const float* __restrict__ psb, float* __restrict__ outs,
        const float* __restrict__ pos, const float* __restrict__ ew,
        float* __restrict__ pb) {
    __shared__ __align__(16) float smem[12672];   // 3 planes x 32 chunks x 132
    __shared__ float Msh[72], Tsh[72];
    int tid = threadIdx.x;
    if (blockIdx.x < 512) {
        // ---- kG ----
        // stage sn into chunked planes: plane ch at ch*4224, chunk c stride 132
        for (int i4 = tid; i4 < 3072; i4 += 256) {
            int ch = i4 >> 10, j = i4 & 1023;
            int m = j * 4;
            int c = m >> 7, rm = m & 127;
            float4 v = ((const float4*)snG)[i4];
            *(float4*)&smem[ch*4224 + c*132 + rm] = v;
        }
        if (tid < 72) Msh[tid] = MT[tid];
        else if (tid < 144) Tsh[tid - 72] = MT[tid];
        __syncthreads();

        int nl = tid >> 5, c = tid & 31;          // 8 n x 32 chunks
        int n = blockIdx.x*8 + nl;
        float x0 = smem[(n>>7)*132 + (n&127)];
        float x1 = smem[4224 + (n>>7)*132 + (n&127)];
        float x2 = smem[8448 + (n>>7)*132 + (n&127)];
        float a0[8], a1[8], a2[8];
#pragma unroll
        for (int h = 0; h < 8; ++h) {
            const float* M = &Msh[h*9];
            a0[h] = x0*M[0] + x1*M[3] + x2*M[6];
            a1[h] = x0*M[1] + x1*M[4] + x2*M[7];
            a2[h] = x0*M[2] + x1*M[5] + x2*M[8];
        }
        float Z[8], S0[8], S1[8], S2[8];
#pragma unroll
        for (int h = 0; h < 8; ++h) { Z[h]=0.f; S0[h]=0.f; S1[h]=0.f; S2[h]=0.f; }
        const float4* p0 = (const float4*)&smem[c*132];
        const float4* p1 = (const float4*)&smem[4224 + c*132];
        const float4* p2 = (const float4*)&smem[8448 + c*132];
        for (int t = 0; t < 32; ++t) {
            float4 v0 = p0[t], v1 = p1[t], v2 = p2[t];
#pragma unroll
            for (int mm = 0; mm < 4; ++mm) {
                float w0 = (mm==0)?v0.x:(mm==1)?v0.y:(mm==2)?v0.z:v0.w;
                float w1 = (mm==0)?v1.x:(mm==1)?v1.y:(mm==2)?v1.z:v1.w;
                float w2 = (mm==0)?v2.x:(mm==1)?v2.y:(mm==2)?v2.z:v2.w;
#pragma unroll
                for (int h = 0; h < 8; ++h) {
                    float e = EXP2(fmaf(a0[h], w0, fmaf(a1[h], w1, a2[h]*w2)));
                    Z[h] += e;
                    S0[h] = fmaf(e, w0, S0[h]);
                    S1[h] = fmaf(e, w1, S1[h]);
                    S2[h] = fmaf(e, w2, S2[h]);
                }
            }
        }
#pragma unroll
        for (int h = 0; h < 8; ++h) {
#pragma unroll
            for (int o = 1; o <= 16; o <<= 1) {
                Z[h]  += __shfl_xor(Z[h], o);
                S0[h] += __shfl_xor(S0[h], o);
                S1[h] += __shfl_xor(S1[h], o);
                S2[h] += __shfl_xor(S2[h], o);
            }
        }
        if (c == 0) {
            float o0 = 0.f, o1 = 0.f, o2 = 0.f;
#pragma unroll
            for (int h = 0; h < 8; ++h) {
                float inv = 1.f / Z[h];
                float r0 = S0[h]*inv, r1 = S1[h]*inv, r2 = S2[h]*inv;
                const float* T = &Tsh[h*9];
                o0 += r0*T[0] + r1*T[3] + r2*T[6];
                o1 += r0*T[1] + r1*T[4] + r2*T[7];
                o2 += r0*T[2] + r1*T[5] + r2*T[8];
            }
            outs[n]        = o0 + psb[0];
            outs[NPIX+n]   = o1 + psb[1];
            outs[2*NPIX+n] = o2 + psb[2];
        }
    } else {
        // ---- kC1: pb[t][o] += sum_{k in 48-chunk} patchvec_t[k] ew[o][k]
        int bb = blockIdx.x - 512;
        int och = bb % 3, ks = bb / 3;        // 16 k-splits of 48
        int k0 = ks * 48;
        float* pv = smem;                     // [16][48]
        for (int idx = tid; idx < 768; idx += 256) {
            int t = idx / 48, k = idx % 48;
            int kk = k0 + k;
            int cc = kk >> 8, pp = (kk >> 4) & 15, q = kk & 15;
            int hp = t >> 2, wp = t & 3;
            pv[idx] = pos[cc*NPIX + (hp*16 + pp)*64 + wp*16 + q];
        }
        __syncthreads();
        int o = och*256 + tid;
        float acc[16];
#pragma unroll
        for (int t = 0; t < 16; ++t) acc[t] = 0.f;
        const float4* wr = (const float4*)(ew + o*768 + k0);
#pragma unroll 3
        for (int k4 = 0; k4 < 12; ++k4) {
            float4 w4 = wr[k4];
#pragma unroll
            for (int t = 0; t < 16; ++t) {
                const float* p4 = &pv[t*48 + k4*4];
                acc[t] = fmaf(w4.x, p4[0], acc[t]);
                acc[t] = fmaf(w4.y, p4[1], acc[t]);
                acc[t] = fmaf(w4.z, p4[2], acc[t]);
                acc[t] = fmaf(w4.w, p4[3], acc[t]);
            }
        }
#pragma unroll
        for (int t = 0; t < 16; ++t) atomicAdd(&pb[t*768 + o], acc[t]);
    }
}

// ================================================================ kC2
__global__ void kC2(const float* __restrict__ pb, const float* __restrict__ eb,
                    const float* __restrict__ g, const float* __restrict__ bb,
                    float* __restrict__ pn) {
    __shared__ float rs[12], rs2[12], stats[2];
    int t = blockIdx.x, tid = threadIdx.x;
    float v = pb[t*768 + tid] + eb[tid];
    float s = v, s2 = v*v;
#pragma unroll
    for (int o = 32; o >= 1; o >>= 1) { s += __shfl_xor(s, o); s2 += __shfl_xor(s2, o); }
    int wid = tid >> 6;
    if ((tid & 63) == 0) { rs[wid] = s; rs2[wid] = s2; }
    __syncthreads();
    if (tid == 0) {
        float S = 0.f, S2 = 0.f;
        for (int i = 0; i < 12; ++i) { S += rs[i]; S2 += rs2[i]; }
        float mu = S * (1.f/768.f);
        stats[0] = mu;
        stats[1] = rsqrtf(fmaxf(S2 * (1.f/768.f) - mu*mu, 0.f) + 1e-5f);
    }
    __syncthreads();
    pn[t*768 + tid] = (v - stats[0]) * stats[1] * g[tid] + bb[tid];
}

// ================================================================ kD
// qkv partial sums: 96 blocks = 3 och x 32 k-splits(24)
__global__ void kD(const float* __restrict__ pn, const float* __restrict__ qw,
                   float* __restrict__ qkvp) {
    __shared__ float ps[16*24];
    int och = blockIdx.x % 3, ks = blockIdx.x / 3;
    int k0 = ks * 24, tid = threadIdx.x;
    for (int idx = tid; idx < 384; idx += 256) {
        int t = idx / 24, k = idx % 24;
        ps[idx] = pn[t*768 + k0 + k];
    }
    __syncthreads();
    int o = och*256 + tid;
    float acc[16];
#pragma unroll
    for (int t = 0; t < 16; ++t) acc[t] = 0.f;
    for (int k = 0; k < 24; ++k) {
        float w = qw[(k0 + k)*768 + o];
#pragma unroll
        for (int t = 0; t < 16; ++t) acc[t] = fmaf(ps[t*24 + k], w, acc[t]);
    }
#pragma unroll
    for (int t = 0; t < 16; ++t) atomicAdd(&qkvp[t*768 + o], acc[t]);
}

// ================================================================ kF1
// fused patch attention (2 heads per block) + projection k-slice.
// 12 blocks = 3 och x 4 ks(64-wide k-slices == head pairs)
__global__ __launch_bounds__(256) void kF1(const float* __restrict__ qkvp,
                                           const float* __restrict__ pw,
                                           float* __restrict__ op) {
    __shared__ float qsl[16*64], ksl[16*64], vsl[16*64], scl[512], att[16*64];
    int och = blockIdx.x % 3, ks = blockIdx.x / 3;
    int tid = threadIdx.x;
    for (int idx = tid; idx < 1024; idx += 256) {
        int t = idx >> 6, j = idx & 63;
        qsl[idx] = qkvp[t*768 + ks*64 + j];
        ksl[idx] = qkvp[t*768 + 256 + ks*64 + j];
        vsl[idx] = qkvp[t*768 + 512 + ks*64 + j];
    }
    __syncthreads();
    // scores: 2 per thread
#pragma unroll
    for (int r = 0; r < 2; ++r) {
        int sidx = tid*2 + r;
        int hh = sidx >> 8, nn = (sidx >> 4) & 15, m = sidx & 15;
        float d = 0.f;
        const float* q = &qsl[nn*64 + hh*32];
        const float* k = &ksl[m*64 + hh*32];
#pragma unroll
        for (int dd = 0; dd < 32; ++dd) d = fmaf(q[dd], k[dd], d);
        scl[sidx] = d * 0.17677669529663687f;
    }
    __syncthreads();
    if (tid < 32) {
        int hh = tid >> 4, nn = tid & 15;
        float* row = &scl[hh*256 + nn*16];
        float mx = row[0];
#pragma unroll
        for (int m = 1; m < 16; ++m) mx = fmaxf(mx, row[m]);
        float s = 0.f;
#pragma unroll
        for (int m = 0; m < 16; ++m) { float e = expf(row[m] - mx); row[m] = e; s += e; }
        float inv = 1.f / s;
#pragma unroll
        for (int m = 0; m < 16; ++m) row[m] *= inv;
    }
    __syncthreads();
    // att[n][j] = sum_m w[j>>5][n][m] * vsl[m][j]   (4 n per thread)
    {
        int j = tid & 63, ng = tid >> 6;
        int hh = j >> 5;
#pragma unroll
        for (int nn = ng*4; nn < ng*4 + 4; ++nn) {
            float acc = 0.f;
#pragma unroll
            for (int m = 0; m < 16; ++m)
                acc = fmaf(scl[hh*256 + nn*16 + m], vsl[m*64 + j], acc);
            att[nn*64 + j] = acc;
        }
    }
    __syncthreads();
    int o = och*256 + tid;
    float acc[16];
#pragma unroll
    for (int t = 0; t < 16; ++t) acc[t] = 0.f;
    for (int k = 0; k < 64; ++k) {
        float w = pw[(ks*64 + k)*768 + o];
#pragma unroll
        for (int t = 0; t < 16; ++t) acc[t] = fmaf(att[t*64 + k], w, acc[t]);
    }
#pragma unroll
    for (int t = 0; t < 16; ++t) atomicAdd(&op[t*768 + o], acc[t]);
}

// ================================================================ kF2
// recon conv-transpose einsum partials: 48 blocks = 3 dij x 16 c-splits(48)
__global__ void kF2(const float* __restrict__ op, const float* __restrict__ ppb,
                    const float* __restrict__ rw, float* __restrict__ outp) {
    __shared__ float os_[16*48];
    int dch = blockIdx.x % 3, cs = blockIdx.x / 3;
    int c0 = cs * 48, tid = threadIdx.x;
    for (int idx = tid; idx < 768; idx += 256) {
        int t = idx / 48, k = idx % 48;
        os_[idx] = op[t*768 + c0 + k] + ppb[c0 + k];
    }
    __syncthreads();
    int dij = dch*256 + tid;
    float acc[16];
#pragma unroll
    for (int t = 0; t < 16; ++t) acc[t] = 0.f;
    for (int k = 0; k < 48; ++k) {
        float w = rw[(c0 + k)*768 + dij];
#pragma unroll
        for (int t = 0; t < 16; ++t) acc[t] = fmaf(os_[t*48 + k], w, acc[t]);
    }
    int d = dij >> 8, i = (dij >> 4) & 15, j = dij & 15;
#pragma unroll
    for (int t = 0; t < 16; ++t) {
        int hp = t >> 2, wp = t & 3;
        atomicAdd(&outp[d*NPIX + (hp*16 + i)*64 + wp*16 + j], acc[t]);
    }
}

// ================================================================ kHI
// combined = outp + rb + outs ; t2 = gelu(conv(combined,pd_w1)) [halo LDS] ;
// out = conv(t2, pd_w2)
__global__ __launch_bounds__(256) void kHI(
        const float* __restrict__ outp, const float* __restrict__ outs,
        const float* __restrict__ rb, const float* __restrict__ w1,
        const float* __restrict__ w2, float* __restrict__ out) {
    __shared__ float t2l[3][8][64];
    int b = blockIdx.x, tid = threadIdx.x;
    int y0 = b * 4;
    for (int i = tid; i < 1536; i += 256) {
        int c = i >> 9, rr = (i >> 6) & 7, xx = i & 63;
        int yg = y0 - 2 + rr;
        float v = 0.f;
        if (yg >= 0 && yg < 64) {
            float acc = 0.f;
#pragma unroll
            for (int ci = 0; ci < 3; ++ci) {
                float bias = rb[ci];
#pragma unroll
                for (int dy = 0; dy < 3; ++dy) {
                    int yy = yg + dy - 1;
                    if (yy < 0 || yy >= 64) continue;
#pragma unroll
                    for (int dx = 0; dx < 3; ++dx) {
                        int xc = xx + dx - 1;
                        if (xc < 0 || xc >= 64) continue;
                        float cb = outp[ci*NPIX + yy*64 + xc] + bias
                                 + outs[ci*NPIX + yy*64 + xc];
                        acc = fmaf(cb, w1[c*27 + ci*9 + dy*3 + dx], acc);
                    }
                }
            }
            v = gelu_exact(acc);
        }
        t2l[c][rr][xx] = v;
    }
    __syncthreads();
    int yl = tid >> 6, xx = tid & 63;
    int yg = y0 + yl;
#pragma unroll
    for (int o = 0; o < 3; ++o) {
        float acc = 0.f;
#pragma unroll
        for (int ci = 0; ci < 3; ++ci) {
#pragma unroll
            for (int dy = 0; dy < 3; ++dy) {
                int yy = yg + dy - 1;
                if (yy < 0 || yy >= 64) continue;
                int rl = yl + dy + 1;
#pragma unroll
                for (int dx = 0; dx < 3; ++dx) {
                    int xc = xx + dx - 1;
                    if (xc < 0 || xc >= 64) continue;
                    acc = fmaf(t2l[ci][rl][xc], w2[o*27 + ci*9 + dy*3 + dx], acc);
                }
            }
        }
        out[o*NPIX + yg*64 + xx] = acc;
    }
}

extern "C" void kernel_launch(void* const* d_in, const int* in_sizes, int n_in,
                              void* d_out, int out_size, void* d_ws, size_t ws_size,
                              hipStream_t stream) {
    (void)in_sizes; (void)n_in; (void)out_size; (void)ws_size;
    const float* x    = (const float*)d_in[0];
    const float* pew1 = (const float*)d_in[1];
    const float* pew2 = (const float*)d_in[2];
    const float* ew   = (const float*)d_in[3];
    const float* eb   = (const float*)d_in[4];
    const float* g1   = (const float*)d_in[5];
    const float* b1   = (const float*)d_in[6];
    const float* qpw  = (const float*)d_in[7];
    const float* ppw  = (const float*)d_in[8];
    const float* ppb  = (const float*)d_in[9];
    const float* rw   = (const float*)d_in[10];
    const float* rb   = (const float*)d_in[11];
    const float* g2   = (const float*)d_in[12];
    const float* b2   = (const float*)d_in[13];
    const float* qsw  = (const float*)d_in[14];
    const float* psw  = (const float*)d_in[15];
    const float* psb  = (const float*)d_in[16];
    const float* pdw1 = (const float*)d_in[17];
    const float* pdw2 = (const float*)d_in[18];

    float* ws   = (float*)d_ws;
    float* pos  = ws;            // 12288
    float* sn   = ws + 12288;    // 12288
    float* MT   = ws + 24576;    // 144
    float* pb   = ws + 24832;    // 12288 (atomic)
    float* pn   = ws + 37120;    // 12288
    float* qkvp = ws + 49408;    // 12288 (atomic)
    float* op   = ws + 61696;    // 12288 (atomic)
    float* outp = ws + 73984;    // 12288 (atomic)
    float* outs = ws + 86272;    // 12288
    float* out  = (float*)d_out;

    kAB<<<dim3(17),  dim3(256), 0, stream>>>(x, pew1, pew2, g2, b2, qsw, psw,
                                             pos, sn, MT, pb, qkvp, op, outp);
    K2 <<<dim3(560), dim3(256), 0, stream>>>(sn, MT, psb, outs, pos, ew, pb);
    kC2<<<dim3(16),  dim3(768), 0, stream>>>(pb, eb, g1, b1, pn);
    kD <<<dim3(96),  dim3(256), 0, stream>>>(pn, qpw, qkvp);
    kF1<<<dim3(12),  dim3(256), 0, stream>>>(qkvp, ppw, op);
    kF2<<<dim3(48),  dim3(256), 0, stream>>>(op, ppb, rw, outp);
    kHI<<<dim3(16),  dim3(256), 0, stream>>>(outp, outs, rb, pdw1, pdw2, out);
}